// Round 1
// baseline (952.217 us; speedup 1.0000x reference)
//
#include <hip/hip_runtime.h>
#include <stdint.h>

#define NN 65536

typedef __attribute__((ext_vector_type(8))) short bf16x8;
typedef __attribute__((ext_vector_type(4))) float f32x4;

__device__ __forceinline__ unsigned short f2bf(float f) {
    unsigned u = __float_as_uint(f);
    u += 0x7fffu + ((u >> 16) & 1u);
    return (unsigned short)(u >> 16);
}
__device__ __forceinline__ float bf2f(unsigned short h) { return __uint_as_float(((unsigned)h) << 16); }
__device__ __forceinline__ float blo(unsigned u) { return __uint_as_float(u << 16); }
__device__ __forceinline__ float bhi(unsigned u) { return __uint_as_float(u & 0xffff0000u); }
__device__ __forceinline__ unsigned pack2(float a, float b) {
    return ((unsigned)f2bf(b) << 16) | (unsigned)f2bf(a);
}

__device__ __forceinline__ void gl_lds16(const void* g, void* l) {
    __builtin_amdgcn_global_load_lds((const __attribute__((address_space(1))) void*)g,
                                     (__attribute__((address_space(3))) void*)l, 16, 0, 0);
}

// ---------------- prep: pack/transpose weights to bf16 ----------------
__global__ void prep_pack(const float* Wt1, const float* Wt2, const float* W1,
                          const float* W2, const float* Mtx,
                          unsigned short* Wcat, unsigned short* W1T,
                          unsigned short* W2T, unsigned short* MTh, unsigned short* MTl) {
    int i = blockIdx.x * 256 + threadIdx.x;
    if (i < 524288) {                       // Wcat [1024][512]
        int k = i >> 9, j = i & 511;
        float v = (k < 256) ? Wt1[k * 512 + j] : Wt2[(k - 256) * 512 + j];
        Wcat[i] = f2bf(v);
    } else if (i < 786432) {                // W1T [512][512]
        int t = i - 524288; int n = t >> 9, j = t & 511;
        W1T[t] = f2bf(W1[j * 512 + n]);
    } else if (i < 851968) {                // W2T [128][512]
        int t = i - 786432; int n = t >> 9, j = t & 511;
        W2T[t] = f2bf(W2[j * 128 + n]);
    } else if (i < 868352) {                // MT [128][128] hi/lo, MT[r][c]=M[c][r]
        int t = i - 851968; int d = t >> 7, e = t & 127;
        float m = Mtx[e * 128 + d];
        unsigned short h = f2bf(m);
        MTh[t] = h; MTl[t] = f2bf(m - bf2f(h));
    }
}

__global__ void cbias_k(const float* bt1, const float* bt2, const float* W1, float* c) {
    int n = blockIdx.x * 256 + threadIdx.x;   // 512 total
    float acc = 0.f;
    for (int j = 0; j < 512; j++) acc += (bt1[j] + bt2[j]) * W1[j * 512 + n];
    c[n] = acc;
}

// ---------------- CSR build ----------------
__global__ void count_k(const int* dst, int* cnt, int E) {
    int e = blockIdx.x * 256 + threadIdx.x;
    if (e < E) atomicAdd(&cnt[dst[e]], 1);
}
__global__ void red_k(const int* cnt, int* bsum) {
    __shared__ int sm[256];
    int tid = threadIdx.x;
    sm[tid] = cnt[blockIdx.x * 256 + tid];
    __syncthreads();
    for (int s = 128; s > 0; s >>= 1) {
        if (tid < s) sm[tid] += sm[tid + s];
        __syncthreads();
    }
    if (tid == 0) bsum[blockIdx.x] = sm[0];
}
__global__ void scanb_k(const int* bsum, int* boff) {
    __shared__ int sm[256];
    int tid = threadIdx.x;
    int v0 = bsum[tid];
    sm[tid] = v0;
    __syncthreads();
    for (int s = 1; s < 256; s <<= 1) {
        int t = sm[tid];
        if (tid >= s) t += sm[tid - s];
        __syncthreads();
        sm[tid] = t;
        __syncthreads();
    }
    boff[tid] = sm[tid] - v0;   // exclusive
}
__global__ void scanf_k(const int* cnt, const int* boff, int* rowptr, int* cursor, float* invs) {
    __shared__ int sm[256];
    int tid = threadIdx.x;
    int i = blockIdx.x * 256 + tid;
    int v = cnt[i];
    sm[tid] = v;
    __syncthreads();
    for (int s = 1; s < 256; s <<= 1) {
        int t = sm[tid];
        if (tid >= s) t += sm[tid - s];
        __syncthreads();
        sm[tid] = t;
        __syncthreads();
    }
    int incl = sm[tid];
    int base = boff[blockIdx.x];
    int excl = base + incl - v;
    rowptr[i] = excl;
    cursor[i] = excl;
    invs[i] = rsqrtf((float)(v + 1));
    if (i == NN - 1) rowptr[NN] = base + incl;
}
__global__ void fill_k(const int* src, const int* dst, int* cursor, int* colv, int E) {
    int e = blockIdx.x * 256 + threadIdx.x;
    if (e < E) {
        int d = dst[e];
        int p = atomicAdd(&cursor[d], 1);
        colv[p] = src[e];
    }
}

// ---------------- generic bf16 GEMM: C[M,N] = A[M,K] @ BT[N,K]^T (+bias[col]) ----------------
__global__ __launch_bounds__(256, 2) void gemm_bt(const unsigned short* A, const unsigned short* BT,
                                                  unsigned short* C, const float* bias,
                                                  int M, int N, int K) {
    __shared__ __align__(16) unsigned short sA[128 * 32];
    __shared__ __align__(16) unsigned short sB[128 * 32];
    int tid = threadIdx.x, wave = tid >> 6, lane = tid & 63;
    int bm = blockIdx.y * 128, bn = blockIdx.x * 128;
    int wm = (wave >> 1) * 64, wn = (wave & 1) * 64;
    f32x4 acc[4][4];
#pragma unroll
    for (int i = 0; i < 4; i++)
#pragma unroll
        for (int j = 0; j < 4; j++) acc[i][j] = (f32x4){0.f, 0.f, 0.f, 0.f};
    int sr = wave * 32 + (lane >> 2);
    int sc = (lane & 3) * 8;
    const int fr = lane & 15;
    const int fk = (lane >> 4) * 8;
    for (int k0 = 0; k0 < K; k0 += 32) {
        const unsigned short* ga = A + (size_t)(bm + sr) * K + k0 + sc;
        gl_lds16(ga, &sA[sr * 32 + sc]);
        gl_lds16(ga + (size_t)16 * K, &sA[(sr + 16) * 32 + sc]);
        const unsigned short* gb = BT + (size_t)(bn + sr) * K + k0 + sc;
        gl_lds16(gb, &sB[sr * 32 + sc]);
        gl_lds16(gb + (size_t)16 * K, &sB[(sr + 16) * 32 + sc]);
        __syncthreads();
        bf16x8 af[4], bfr[4];
#pragma unroll
        for (int i = 0; i < 4; i++) af[i] = *(const bf16x8*)&sA[(wm + i * 16 + fr) * 32 + fk];
#pragma unroll
        for (int j = 0; j < 4; j++) bfr[j] = *(const bf16x8*)&sB[(wn + j * 16 + fr) * 32 + fk];
#pragma unroll
        for (int i = 0; i < 4; i++)
#pragma unroll
            for (int j = 0; j < 4; j++)
                acc[i][j] = __builtin_amdgcn_mfma_f32_16x16x32_bf16(af[i], bfr[j], acc[i][j], 0, 0, 0);
        __syncthreads();
    }
    int rq = (lane >> 4) * 4;
#pragma unroll
    for (int i = 0; i < 4; i++)
#pragma unroll
        for (int j = 0; j < 4; j++) {
            int col = bn + wn + j * 16 + fr;
            float bb = bias ? bias[col] : 0.f;
#pragma unroll
            for (int r = 0; r < 4; r++) {
                int row = bm + wm + i * 16 + rq + r;
                C[(size_t)row * N + col] = f2bf(acc[i][j][r] + bb);
            }
        }
}

// ---------------- GEMM1: A is fp32 (x), manual A staging; B async ----------------
__global__ __launch_bounds__(256, 2) void gemm_f32a(const float* A, const unsigned short* BT,
                                                    unsigned short* C, const float* bias,
                                                    int M, int N, int K) {
    __shared__ __align__(16) unsigned short sA[128 * 32];
    __shared__ __align__(16) unsigned short sB[128 * 32];
    int tid = threadIdx.x, wave = tid >> 6, lane = tid & 63;
    int bm = blockIdx.y * 128, bn = blockIdx.x * 128;
    int wm = (wave >> 1) * 64, wn = (wave & 1) * 64;
    f32x4 acc[4][4];
#pragma unroll
    for (int i = 0; i < 4; i++)
#pragma unroll
        for (int j = 0; j < 4; j++) acc[i][j] = (f32x4){0.f, 0.f, 0.f, 0.f};
    int sr = wave * 32 + (lane >> 2);
    int sc = (lane & 3) * 8;
    const int fr = lane & 15;
    const int fk = (lane >> 4) * 8;
    for (int k0 = 0; k0 < K; k0 += 32) {
#pragma unroll
        for (int i = 0; i < 4; i++) {
            int idx = tid + 256 * i;
            int row = idx >> 3, cg = idx & 7;
            float4 v = *(const float4*)&A[(size_t)(bm + row) * K + k0 + cg * 4];
            ushort4 pk;
            pk.x = f2bf(v.x); pk.y = f2bf(v.y); pk.z = f2bf(v.z); pk.w = f2bf(v.w);
            *(ushort4*)&sA[row * 32 + cg * 4] = pk;
        }
        const unsigned short* gb = BT + (size_t)(bn + sr) * K + k0 + sc;
        gl_lds16(gb, &sB[sr * 32 + sc]);
        gl_lds16(gb + (size_t)16 * K, &sB[(sr + 16) * 32 + sc]);
        __syncthreads();
        bf16x8 af[4], bfr[4];
#pragma unroll
        for (int i = 0; i < 4; i++) af[i] = *(const bf16x8*)&sA[(wm + i * 16 + fr) * 32 + fk];
#pragma unroll
        for (int j = 0; j < 4; j++) bfr[j] = *(const bf16x8*)&sB[(wn + j * 16 + fr) * 32 + fk];
#pragma unroll
        for (int i = 0; i < 4; i++)
#pragma unroll
            for (int j = 0; j < 4; j++)
                acc[i][j] = __builtin_amdgcn_mfma_f32_16x16x32_bf16(af[i], bfr[j], acc[i][j], 0, 0, 0);
        __syncthreads();
    }
    int rq = (lane >> 4) * 4;
#pragma unroll
    for (int i = 0; i < 4; i++)
#pragma unroll
        for (int j = 0; j < 4; j++) {
            int col = bn + wn + j * 16 + fr;
            float bb = bias ? bias[col] : 0.f;
#pragma unroll
            for (int r = 0; r < 4; r++) {
                int row = bm + wm + i * 16 + rq + r;
                C[(size_t)row * N + col] = f2bf(acc[i][j][r] + bb);
            }
        }
}

// ---------------- T = h2 @ M with hi/lo split (3 phases), split output ----------------
__global__ __launch_bounds__(256, 2) void gemm_T(const unsigned short* h2h, const unsigned short* h2l,
                                                 const unsigned short* MTh, const unsigned short* MTl,
                                                 unsigned short* Th, unsigned short* Tl) {
    __shared__ __align__(16) unsigned short sA[128 * 32];
    __shared__ __align__(16) unsigned short sB[128 * 32];
    int tid = threadIdx.x, wave = tid >> 6, lane = tid & 63;
    int bm = blockIdx.x * 128;
    int wm = (wave >> 1) * 64, wn = (wave & 1) * 64;
    f32x4 acc[4][4];
#pragma unroll
    for (int i = 0; i < 4; i++)
#pragma unroll
        for (int j = 0; j < 4; j++) acc[i][j] = (f32x4){0.f, 0.f, 0.f, 0.f};
    int sr = wave * 32 + (lane >> 2);
    int sc = (lane & 3) * 8;
    const int fr = lane & 15;
    const int fk = (lane >> 4) * 8;
    const unsigned short* APs[3] = {h2h, h2h, h2l};
    const unsigned short* BPs[3] = {MTh, MTl, MTh};
    for (int it = 0; it < 12; it++) {
        int ph = it >> 2, k0 = (it & 3) * 32;
        const unsigned short* ga = APs[ph] + (size_t)(bm + sr) * 128 + k0 + sc;
        gl_lds16(ga, &sA[sr * 32 + sc]);
        gl_lds16(ga + 16 * 128, &sA[(sr + 16) * 32 + sc]);
        const unsigned short* gb = BPs[ph] + (size_t)sr * 128 + k0 + sc;
        gl_lds16(gb, &sB[sr * 32 + sc]);
        gl_lds16(gb + 16 * 128, &sB[(sr + 16) * 32 + sc]);
        __syncthreads();
        bf16x8 af[4], bfr[4];
#pragma unroll
        for (int i = 0; i < 4; i++) af[i] = *(const bf16x8*)&sA[(wm + i * 16 + fr) * 32 + fk];
#pragma unroll
        for (int j = 0; j < 4; j++) bfr[j] = *(const bf16x8*)&sB[(wn + j * 16 + fr) * 32 + fk];
#pragma unroll
        for (int i = 0; i < 4; i++)
#pragma unroll
            for (int j = 0; j < 4; j++)
                acc[i][j] = __builtin_amdgcn_mfma_f32_16x16x32_bf16(af[i], bfr[j], acc[i][j], 0, 0, 0);
        __syncthreads();
    }
    int rq = (lane >> 4) * 4;
#pragma unroll
    for (int i = 0; i < 4; i++)
#pragma unroll
        for (int j = 0; j < 4; j++) {
            int col = wn + j * 16 + fr;
#pragma unroll
            for (int r = 0; r < 4; r++) {
                int row = bm + wm + i * 16 + rq + r;
                float v = acc[i][j][r];
                unsigned short h = f2bf(v);
                Th[(size_t)row * 128 + col] = h;
                Tl[(size_t)row * 128 + col] = f2bf(v - bf2f(h));
            }
        }
}

// ---------------- aggregation, 512-dim, +bias, relu, bf16 out ----------------
__global__ __launch_bounds__(256) void agg512(const unsigned short* t, const int* rowptr,
                                              const int* colv, const float* invs,
                                              const float* bias, unsigned short* outp) {
    int wave = threadIdx.x >> 6, lane = threadIdx.x & 63;
    int node = blockIdx.x * 4 + wave;
    int d0 = lane * 8;
    float acc[8] = {0.f, 0.f, 0.f, 0.f, 0.f, 0.f, 0.f, 0.f};
    int r0 = rowptr[node], r1 = rowptr[node + 1];
    for (int e = r0; e < r1; e++) {
        int s = colv[e];
        float ws = invs[s];
        uint4 v = *(const uint4*)&t[(size_t)s * 512 + d0];
        acc[0] += ws * blo(v.x); acc[1] += ws * bhi(v.x);
        acc[2] += ws * blo(v.y); acc[3] += ws * bhi(v.y);
        acc[4] += ws * blo(v.z); acc[5] += ws * bhi(v.z);
        acc[6] += ws * blo(v.w); acc[7] += ws * bhi(v.w);
    }
    float wd = invs[node], wdd = wd * wd;
    uint4 sv = *(const uint4*)&t[(size_t)node * 512 + d0];
    float sf[8] = {blo(sv.x), bhi(sv.x), blo(sv.y), bhi(sv.y), blo(sv.z), bhi(sv.z), blo(sv.w), bhi(sv.w)};
    float o[8];
#pragma unroll
    for (int k = 0; k < 8; k++) {
        float v = acc[k] * wd + sf[k] * wdd + bias[d0 + k];
        o[k] = v > 0.f ? v : 0.f;
    }
    uint4 pv;
    pv.x = pack2(o[0], o[1]); pv.y = pack2(o[2], o[3]);
    pv.z = pack2(o[4], o[5]); pv.w = pack2(o[6], o[7]);
    *(uint4*)&outp[(size_t)node * 512 + d0] = pv;
}

// ---------------- aggregation, 128-dim, +bias, hi/lo split out ----------------
__global__ __launch_bounds__(256) void agg128(const unsigned short* u, const int* rowptr,
                                              const int* colv, const float* invs,
                                              const float* bias, unsigned short* h2h, unsigned short* h2l) {
    int wave = threadIdx.x >> 6, lane = threadIdx.x & 63;
    int node = blockIdx.x * 4 + wave;
    int q = lane >> 4, ql = lane & 15;
    int d0 = ql * 8;
    float acc[8] = {0.f, 0.f, 0.f, 0.f, 0.f, 0.f, 0.f, 0.f};
    int r0 = rowptr[node], r1 = rowptr[node + 1];
    for (int e = r0 + q; e < r1; e += 4) {
        int s = colv[e];
        float ws = invs[s];
        uint4 v = *(const uint4*)&u[(size_t)s * 128 + d0];
        acc[0] += ws * blo(v.x); acc[1] += ws * bhi(v.x);
        acc[2] += ws * blo(v.y); acc[3] += ws * bhi(v.y);
        acc[4] += ws * blo(v.z); acc[5] += ws * bhi(v.z);
        acc[6] += ws * blo(v.w); acc[7] += ws * bhi(v.w);
    }
#pragma unroll
    for (int k = 0; k < 8; k++) {
        acc[k] += __shfl_xor(acc[k], 16);
        acc[k] += __shfl_xor(acc[k], 32);
    }
    float wd = invs[node], wdd = wd * wd;
    uint4 sv = *(const uint4*)&u[(size_t)node * 128 + d0];
    float sf[8] = {blo(sv.x), bhi(sv.x), blo(sv.y), bhi(sv.y), blo(sv.z), bhi(sv.z), blo(sv.w), bhi(sv.w)};
    unsigned short hh[8], hl[8];
#pragma unroll
    for (int k = 0; k < 8; k++) {
        float v = acc[k] * wd + sf[k] * wdd + bias[d0 + k];
        hh[k] = f2bf(v);
        hl[k] = f2bf(v - bf2f(hh[k]));
    }
    if (q == 0) {
        uint4 ph, pl;
        ph.x = ((unsigned)hh[1] << 16) | hh[0]; ph.y = ((unsigned)hh[3] << 16) | hh[2];
        ph.z = ((unsigned)hh[5] << 16) | hh[4]; ph.w = ((unsigned)hh[7] << 16) | hh[6];
        pl.x = ((unsigned)hl[1] << 16) | hl[0]; pl.y = ((unsigned)hl[3] << 16) | hl[2];
        pl.z = ((unsigned)hl[5] << 16) | hl[4]; pl.w = ((unsigned)hl[7] << 16) | hl[6];
        *(uint4*)&h2h[(size_t)node * 128 + d0] = ph;
        *(uint4*)&h2l[(size_t)node * 128 + d0] = pl;
    }
}

// ---------------- bilinear: s = T @ e^T, out = s*w + b ----------------
__global__ __launch_bounds__(256, 2) void bilinear_k(const unsigned short* Th, const unsigned short* Tl,
                                                     const unsigned short* Eh, const float* lin_w,
                                                     const float* lin_b, float* outp) {
    int tid = threadIdx.x, wave = tid >> 6, lane = tid & 63;
    int b = blockIdx.x >> 1, half = blockIdx.x & 1;
    int fr = lane & 15, q = lane >> 4;
    int irow0 = b * 256 + half * 128 + wave * 32;
    bf16x8 Ah[2][4], Al[2][4];
#pragma unroll
    for (int it = 0; it < 2; it++)
#pragma unroll
        for (int kk = 0; kk < 4; kk++) {
            size_t off = (size_t)(irow0 + it * 16 + fr) * 128 + kk * 32 + q * 8;
            Ah[it][kk] = *(const bf16x8*)&Th[off];
            Al[it][kk] = *(const bf16x8*)&Tl[off];
        }
    float w0 = lin_w[0], w1 = lin_w[1], c0 = lin_b[0], c1 = lin_b[1];
    for (int jt = 0; jt < 16; jt++) {
        bf16x8 Bf[4];
#pragma unroll
        for (int kk = 0; kk < 4; kk++)
            Bf[kk] = *(const bf16x8*)&Eh[(size_t)(b * 256 + jt * 16 + fr) * 128 + kk * 32 + q * 8];
#pragma unroll
        for (int it = 0; it < 2; it++) {
            f32x4 acc = (f32x4){0.f, 0.f, 0.f, 0.f};
#pragma unroll
            for (int kk = 0; kk < 4; kk++) {
                acc = __builtin_amdgcn_mfma_f32_16x16x32_bf16(Ah[it][kk], Bf[kk], acc, 0, 0, 0);
                acc = __builtin_amdgcn_mfma_f32_16x16x32_bf16(Al[it][kk], Bf[kk], acc, 0, 0, 0);
            }
#pragma unroll
            for (int r = 0; r < 4; r++) {
                int iloc = half * 128 + wave * 32 + it * 16 + q * 4 + r;
                int jloc = jt * 16 + fr;
                size_t o = ((size_t)b * 65536 + (size_t)iloc * 256 + jloc) * 2;
                float s = acc[r];
                float2 ov;
                ov.x = fmaf(s, w0, c0);
                ov.y = fmaf(s, w1, c1);
                *(float2*)&outp[o] = ov;
            }
        }
    }
}

extern "C" void kernel_launch(void* const* d_in, const int* in_sizes, int n_in,
                              void* d_out, int out_size, void* d_ws, size_t ws_size,
                              hipStream_t stream) {
    const float* x   = (const float*)d_in[0];
    const float* Wt1 = (const float*)d_in[1];
    const float* bt1 = (const float*)d_in[2];
    const float* Wt2 = (const float*)d_in[3];
    const float* bt2 = (const float*)d_in[4];
    const float* W1  = (const float*)d_in[5];
    const float* b1  = (const float*)d_in[6];
    const float* W2  = (const float*)d_in[7];
    const float* b2  = (const float*)d_in[8];
    const float* Mtx = (const float*)d_in[9];
    const float* lw  = (const float*)d_in[10];
    const float* lb  = (const float*)d_in[11];
    const int*   ei  = (const int*)d_in[12];
    int E = in_sizes[12] / 2;
    const int* srcp = ei;
    const int* dstp = ei + E;

    unsigned char* p = (unsigned char*)d_ws;
    size_t off = 0;
    auto alloc = [&](size_t bytes) -> void* {
        void* r = p + off;
        off = (off + bytes + 255) & ~(size_t)255;
        return r;
    };
    int*   cnt    = (int*)alloc((size_t)NN * 4);
    int*   rowptr = (int*)alloc(((size_t)NN + 1) * 4);
    int*   cursor = (int*)alloc((size_t)NN * 4);
    float* invs   = (float*)alloc((size_t)NN * 4);
    int*   bsum   = (int*)alloc(256 * 4);
    int*   boff   = (int*)alloc(256 * 4);
    int*   colv   = (int*)alloc((size_t)E * 4);
    unsigned short* Wcat   = (unsigned short*)alloc(524288 * 2);
    unsigned short* W1T    = (unsigned short*)alloc(262144 * 2);
    unsigned short* W2T    = (unsigned short*)alloc(65536 * 2);
    unsigned short* MTh    = (unsigned short*)alloc(16384 * 2);
    unsigned short* MTl    = (unsigned short*)alloc(16384 * 2);
    float*          cbias  = (float*)alloc(512 * 4);
    unsigned short* WcombT = (unsigned short*)alloc(524288 * 2);
    unsigned short* t1     = (unsigned short*)alloc((size_t)NN * 512 * 2);
    unsigned short* h1     = (unsigned short*)alloc((size_t)NN * 512 * 2);
    unsigned short* uu     = (unsigned short*)alloc((size_t)NN * 128 * 2);
    // aliases (lifetimes disjoint): T over t1, h2 over h1
    unsigned short* Th  = t1;
    unsigned short* Tl  = t1 + (size_t)NN * 128;
    unsigned short* h2h = h1;
    unsigned short* h2l = h1 + (size_t)NN * 128;

    hipMemsetAsync(cnt, 0, (size_t)NN * 4, stream);
    prep_pack<<<3392, 256, 0, stream>>>(Wt1, Wt2, W1, W2, Mtx, Wcat, W1T, W2T, MTh, MTl);
    cbias_k<<<2, 256, 0, stream>>>(bt1, bt2, W1, cbias);
    count_k<<<(E + 255) / 256, 256, 0, stream>>>(dstp, cnt, E);
    red_k<<<256, 256, 0, stream>>>(cnt, bsum);
    scanb_k<<<1, 256, 0, stream>>>(bsum, boff);
    scanf_k<<<256, 256, 0, stream>>>(cnt, boff, rowptr, cursor, invs);
    fill_k<<<(E + 255) / 256, 256, 0, stream>>>(srcp, dstp, cursor, colv, E);
    // WcombT[512][1024] = (Wcat @ W1)^T = W1T @ Wcat^T
    gemm_bt<<<dim3(8, 4), 256, 0, stream>>>(W1T, Wcat, WcombT, nullptr, 512, 1024, 512);
    // t1 = x @ Wcomb + cbias   [65536,512]
    gemm_f32a<<<dim3(4, 512), 256, 0, stream>>>(x, WcombT, t1, cbias, NN, 512, 1024);
    // h1 = relu(A @ t1 + b1)
    agg512<<<NN / 4, 256, 0, stream>>>(t1, rowptr, colv, invs, b1, h1);
    // u = h1 @ W2   [65536,128]
    gemm_bt<<<dim3(1, 512), 256, 0, stream>>>(h1, W2T, uu, nullptr, NN, 128, 512);
    // h2 = A @ u + b2 (hi/lo split)
    agg128<<<NN / 4, 256, 0, stream>>>(uu, rowptr, colv, invs, b2, h2h, h2l);
    // T = h2 @ M (split)
    gemm_T<<<512, 256, 0, stream>>>(h2h, h2l, MTh, MTl, Th, Tl);
    // scores + Linear(1,2)
    bilinear_k<<<512, 256, 0, stream>>>(Th, Tl, h2h, lw, lb, (float*)d_out);
}

// Round 2
// 938.548 us; speedup vs baseline: 1.0146x; 1.0146x over previous
//
#include <hip/hip_runtime.h>
#include <stdint.h>

#define NN 65536

typedef __attribute__((ext_vector_type(8))) short bf16x8;
typedef __attribute__((ext_vector_type(4))) float f32x4;

__device__ __forceinline__ unsigned short f2bf(float f) {
    unsigned u = __float_as_uint(f);
    u += 0x7fffu + ((u >> 16) & 1u);
    return (unsigned short)(u >> 16);
}
__device__ __forceinline__ float bf2f(unsigned short h) { return __uint_as_float(((unsigned)h) << 16); }
__device__ __forceinline__ float blo(unsigned u) { return __uint_as_float(u << 16); }
__device__ __forceinline__ float bhi(unsigned u) { return __uint_as_float(u & 0xffff0000u); }
__device__ __forceinline__ unsigned pack2(float a, float b) {
    return ((unsigned)f2bf(b) << 16) | (unsigned)f2bf(a);
}

__device__ __forceinline__ void gl_lds16(const void* g, void* l) {
    __builtin_amdgcn_global_load_lds((const __attribute__((address_space(1))) void*)g,
                                     (__attribute__((address_space(3))) void*)l, 16, 0, 0);
}

// ---------------- prep: pack/transpose weights to bf16 ----------------
__global__ void prep_pack(const float* Wt1, const float* Wt2, const float* W1,
                          const float* W2, const float* Mtx,
                          unsigned short* Wcat, unsigned short* W1T,
                          unsigned short* W2T, unsigned short* MTh, unsigned short* MTl) {
    int i = blockIdx.x * 256 + threadIdx.x;
    if (i < 524288) {                       // Wcat [1024][512]
        int k = i >> 9, j = i & 511;
        float v = (k < 256) ? Wt1[k * 512 + j] : Wt2[(k - 256) * 512 + j];
        Wcat[i] = f2bf(v);
    } else if (i < 786432) {                // W1T [512][512]
        int t = i - 524288; int n = t >> 9, j = t & 511;
        W1T[t] = f2bf(W1[j * 512 + n]);
    } else if (i < 851968) {                // W2T [128][512]
        int t = i - 786432; int n = t >> 9, j = t & 511;
        W2T[t] = f2bf(W2[j * 128 + n]);
    } else if (i < 868352) {                // MT [128][128] hi/lo, MT[r][c]=M[c][r]
        int t = i - 851968; int d = t >> 7, e = t & 127;
        float m = Mtx[e * 128 + d];
        unsigned short h = f2bf(m);
        MTh[t] = h; MTl[t] = f2bf(m - bf2f(h));
    }
}

// cbias = (bt1+bt2) @ W1 — 16 blocks, K-partitioned reduction
__global__ void cbias_k(const float* bt1, const float* bt2, const float* W1, float* c) {
    __shared__ float sm[256];
    int t = threadIdx.x;
    int n = blockIdx.x * 32 + (t & 31);
    int jp = t >> 5;                        // 8 K-partitions of 64
    float acc = 0.f;
    for (int j = jp * 64; j < jp * 64 + 64; j++)
        acc += (bt1[j] + bt2[j]) * W1[j * 512 + n];
    sm[t] = acc;
    __syncthreads();
    if (t < 32) {
        float a = 0.f;
#pragma unroll
        for (int p = 0; p < 8; p++) a += sm[p * 32 + t];
        c[blockIdx.x * 32 + t] = a;
    }
}

// ---------------- CSR build ----------------
__global__ void count_k(const int* dst, int* cnt, int E) {
    int e = blockIdx.x * 256 + threadIdx.x;
    if (e < E) atomicAdd(&cnt[dst[e]], 1);
}
__global__ void red_k(const int* cnt, int* bsum) {
    __shared__ int sm[256];
    int tid = threadIdx.x;
    sm[tid] = cnt[blockIdx.x * 256 + tid];
    __syncthreads();
    for (int s = 128; s > 0; s >>= 1) {
        if (tid < s) sm[tid] += sm[tid + s];
        __syncthreads();
    }
    if (tid == 0) bsum[blockIdx.x] = sm[0];
}
__global__ void scanb_k(const int* bsum, int* boff) {
    __shared__ int sm[256];
    int tid = threadIdx.x;
    int v0 = bsum[tid];
    sm[tid] = v0;
    __syncthreads();
    for (int s = 1; s < 256; s <<= 1) {
        int t = sm[tid];
        if (tid >= s) t += sm[tid - s];
        __syncthreads();
        sm[tid] = t;
        __syncthreads();
    }
    boff[tid] = sm[tid] - v0;   // exclusive
}
__global__ void scanf_k(const int* cnt, const int* boff, int* rowptr, int* cursor, float* invs) {
    __shared__ int sm[256];
    int tid = threadIdx.x;
    int i = blockIdx.x * 256 + tid;
    int v = cnt[i];
    sm[tid] = v;
    __syncthreads();
    for (int s = 1; s < 256; s <<= 1) {
        int t = sm[tid];
        if (tid >= s) t += sm[tid - s];
        __syncthreads();
        sm[tid] = t;
        __syncthreads();
    }
    int incl = sm[tid];
    int base = boff[blockIdx.x];
    int excl = base + incl - v;
    rowptr[i] = excl;
    cursor[i] = excl;
    invs[i] = rsqrtf((float)(v + 1));
    if (i == NN - 1) rowptr[NN] = base + incl;
}
__global__ void fill_k(const int* src, const int* dst, int* cursor, int* colv, int E) {
    int e = blockIdx.x * 256 + threadIdx.x;
    if (e < E) {
        int d = dst[e];
        int p = atomicAdd(&cursor[d], 1);
        colv[p] = src[e];
    }
}

// ---------------- generic bf16 GEMM: C[M,N] = A[M,K] @ BT[N,K]^T (+bias[col]) ----------------
__global__ __launch_bounds__(256, 2) void gemm_bt(const unsigned short* A, const unsigned short* BT,
                                                  unsigned short* C, const float* bias,
                                                  int M, int N, int K) {
    __shared__ __align__(16) unsigned short sA[128 * 32];
    __shared__ __align__(16) unsigned short sB[128 * 32];
    int tid = threadIdx.x, wave = tid >> 6, lane = tid & 63;
    int bm = blockIdx.y * 128, bn = blockIdx.x * 128;
    int wm = (wave >> 1) * 64, wn = (wave & 1) * 64;
    f32x4 acc[4][4];
#pragma unroll
    for (int i = 0; i < 4; i++)
#pragma unroll
        for (int j = 0; j < 4; j++) acc[i][j] = (f32x4){0.f, 0.f, 0.f, 0.f};
    int sr = wave * 32 + (lane >> 2);
    int sc = (lane & 3) * 8;
    const int fr = lane & 15;
    const int fk = (lane >> 4) * 8;
    for (int k0 = 0; k0 < K; k0 += 32) {
        const unsigned short* ga = A + (size_t)(bm + sr) * K + k0 + sc;
        gl_lds16(ga, &sA[sr * 32 + sc]);
        gl_lds16(ga + (size_t)16 * K, &sA[(sr + 16) * 32 + sc]);
        const unsigned short* gb = BT + (size_t)(bn + sr) * K + k0 + sc;
        gl_lds16(gb, &sB[sr * 32 + sc]);
        gl_lds16(gb + (size_t)16 * K, &sB[(sr + 16) * 32 + sc]);
        __syncthreads();
        bf16x8 af[4], bfr[4];
#pragma unroll
        for (int i = 0; i < 4; i++) af[i] = *(const bf16x8*)&sA[(wm + i * 16 + fr) * 32 + fk];
#pragma unroll
        for (int j = 0; j < 4; j++) bfr[j] = *(const bf16x8*)&sB[(wn + j * 16 + fr) * 32 + fk];
#pragma unroll
        for (int i = 0; i < 4; i++)
#pragma unroll
            for (int j = 0; j < 4; j++)
                acc[i][j] = __builtin_amdgcn_mfma_f32_16x16x32_bf16(af[i], bfr[j], acc[i][j], 0, 0, 0);
        __syncthreads();
    }
    int rq = (lane >> 4) * 4;
#pragma unroll
    for (int i = 0; i < 4; i++)
#pragma unroll
        for (int j = 0; j < 4; j++) {
            int col = bn + wn + j * 16 + fr;
            float bb = bias ? bias[col] : 0.f;
#pragma unroll
            for (int r = 0; r < 4; r++) {
                int row = bm + wm + i * 16 + rq + r;
                C[(size_t)row * N + col] = f2bf(acc[i][j][r] + bb);
            }
        }
}

// ---------------- GEMM1: t1 = x[65536,1024] @ WcombT^T + cbias ----------------
// fp32 A, register-prefetched A + double-buffered LDS (1 barrier/K-step),
// XCD-swizzled blocks: all 4 bn-tiles of one bm land on the same XCD's L2.
__global__ __launch_bounds__(256, 2) void gemm_f32a(const float* A, const unsigned short* BT,
                                                    unsigned short* C, const float* bias) {
    const int K = 1024, N = 512;
    __shared__ __align__(16) unsigned short sA[2][128 * 32];
    __shared__ __align__(16) unsigned short sB[2][128 * 32];
    int tid = threadIdx.x, wave = tid >> 6, lane = tid & 63;
    int b = blockIdx.x;
    int xcd = b & 7, jn = (b >> 3) & 3, tt = b >> 5;
    int bm = (tt * 8 + xcd) * 128, bn = jn * 128;
    int wm = (wave >> 1) * 64, wn = (wave & 1) * 64;
    f32x4 acc[4][4];
#pragma unroll
    for (int i = 0; i < 4; i++)
#pragma unroll
        for (int j = 0; j < 4; j++) acc[i][j] = (f32x4){0.f, 0.f, 0.f, 0.f};
    int sr = wave * 32 + (lane >> 2);
    int sc = (lane & 3) * 8;
    const int fr = lane & 15;
    const int fk = (lane >> 4) * 8;
    // A staging map: thread covers rows ar+32i, 4 consecutive floats at col ac
    int ar = tid >> 3, ac = (tid & 7) * 4;
    const float* Abase = A + (size_t)(bm + ar) * K + ac;
    const unsigned short* Bbase = BT + (size_t)(bn + sr) * K + sc;
    float4 ra[4];
    auto loadA = [&](int k0) {
#pragma unroll
        for (int i = 0; i < 4; i++)
            ra[i] = *(const float4*)(Abase + (size_t)(32 * i) * K + k0);
    };
    auto stageA = [&](int buf) {
#pragma unroll
        for (int i = 0; i < 4; i++) {
            ushort4 pk;
            pk.x = f2bf(ra[i].x); pk.y = f2bf(ra[i].y); pk.z = f2bf(ra[i].z); pk.w = f2bf(ra[i].w);
            *(ushort4*)&sA[buf][(ar + 32 * i) * 32 + ac] = pk;
        }
    };
    auto stageB = [&](int buf, int k0) {
        gl_lds16(Bbase + k0, &sB[buf][sr * 32 + sc]);
        gl_lds16(Bbase + (size_t)16 * K + k0, &sB[buf][(sr + 16) * 32 + sc]);
    };
    // prologue
    loadA(0);
    stageB(0, 0);
    stageA(0);
    loadA(32);
    __syncthreads();
    for (int k = 0; k < 32; k++) {
        int cur = k & 1, nxt = cur ^ 1;
        if (k < 31) {
            stageB(nxt, (k + 1) * 32);
            stageA(nxt);                    // ra holds A((k+1)*32), already drained
        }
        if (k < 30) loadA((k + 2) * 32);    // in flight across the compute phase
        bf16x8 af[4], bfr[4];
#pragma unroll
        for (int i = 0; i < 4; i++) af[i] = *(const bf16x8*)&sA[cur][(wm + i * 16 + fr) * 32 + fk];
#pragma unroll
        for (int j = 0; j < 4; j++) bfr[j] = *(const bf16x8*)&sB[cur][(wn + j * 16 + fr) * 32 + fk];
#pragma unroll
        for (int i = 0; i < 4; i++)
#pragma unroll
            for (int j = 0; j < 4; j++)
                acc[i][j] = __builtin_amdgcn_mfma_f32_16x16x32_bf16(af[i], bfr[j], acc[i][j], 0, 0, 0);
        __syncthreads();
    }
    int rq = (lane >> 4) * 4;
#pragma unroll
    for (int i = 0; i < 4; i++)
#pragma unroll
        for (int j = 0; j < 4; j++) {
            int col = bn + wn + j * 16 + fr;
            float bb = bias[col];
#pragma unroll
            for (int r = 0; r < 4; r++) {
                int row = bm + wm + i * 16 + rq + r;
                C[(size_t)row * N + col] = f2bf(acc[i][j][r] + bb);
            }
        }
}

// ---------------- T = h2 @ M with hi/lo split (3 phases), split output ----------------
__global__ __launch_bounds__(256, 2) void gemm_T(const unsigned short* h2h, const unsigned short* h2l,
                                                 const unsigned short* MTh, const unsigned short* MTl,
                                                 unsigned short* Th, unsigned short* Tl) {
    __shared__ __align__(16) unsigned short sA[128 * 32];
    __shared__ __align__(16) unsigned short sB[128 * 32];
    int tid = threadIdx.x, wave = tid >> 6, lane = tid & 63;
    int bm = blockIdx.x * 128;
    int wm = (wave >> 1) * 64, wn = (wave & 1) * 64;
    f32x4 acc[4][4];
#pragma unroll
    for (int i = 0; i < 4; i++)
#pragma unroll
        for (int j = 0; j < 4; j++) acc[i][j] = (f32x4){0.f, 0.f, 0.f, 0.f};
    int sr = wave * 32 + (lane >> 2);
    int sc = (lane & 3) * 8;
    const int fr = lane & 15;
    const int fk = (lane >> 4) * 8;
    const unsigned short* APs[3] = {h2h, h2h, h2l};
    const unsigned short* BPs[3] = {MTh, MTl, MTh};
    for (int it = 0; it < 12; it++) {
        int ph = it >> 2, k0 = (it & 3) * 32;
        const unsigned short* ga = APs[ph] + (size_t)(bm + sr) * 128 + k0 + sc;
        gl_lds16(ga, &sA[sr * 32 + sc]);
        gl_lds16(ga + 16 * 128, &sA[(sr + 16) * 32 + sc]);
        const unsigned short* gb = BPs[ph] + (size_t)sr * 128 + k0 + sc;
        gl_lds16(gb, &sB[sr * 32 + sc]);
        gl_lds16(gb + 16 * 128, &sB[(sr + 16) * 32 + sc]);
        __syncthreads();
        bf16x8 af[4], bfr[4];
#pragma unroll
        for (int i = 0; i < 4; i++) af[i] = *(const bf16x8*)&sA[(wm + i * 16 + fr) * 32 + fk];
#pragma unroll
        for (int j = 0; j < 4; j++) bfr[j] = *(const bf16x8*)&sB[(wn + j * 16 + fr) * 32 + fk];
#pragma unroll
        for (int i = 0; i < 4; i++)
#pragma unroll
            for (int j = 0; j < 4; j++)
                acc[i][j] = __builtin_amdgcn_mfma_f32_16x16x32_bf16(af[i], bfr[j], acc[i][j], 0, 0, 0);
        __syncthreads();
    }
    int rq = (lane >> 4) * 4;
#pragma unroll
    for (int i = 0; i < 4; i++)
#pragma unroll
        for (int j = 0; j < 4; j++) {
            int col = wn + j * 16 + fr;
#pragma unroll
            for (int r = 0; r < 4; r++) {
                int row = bm + wm + i * 16 + rq + r;
                float v = acc[i][j][r];
                unsigned short h = f2bf(v);
                Th[(size_t)row * 128 + col] = h;
                Tl[(size_t)row * 128 + col] = f2bf(v - bf2f(h));
            }
        }
}

// ---------------- aggregation, 512-dim, +bias, relu, bf16 out ----------------
__global__ __launch_bounds__(256) void agg512(const unsigned short* t, const int* rowptr,
                                              const int* colv, const float* invs,
                                              const float* bias, unsigned short* outp) {
    int wave = threadIdx.x >> 6, lane = threadIdx.x & 63;
    int node = blockIdx.x * 4 + wave;
    int d0 = lane * 8;
    float acc[8] = {0.f, 0.f, 0.f, 0.f, 0.f, 0.f, 0.f, 0.f};
    int r0 = rowptr[node], r1 = rowptr[node + 1];
    int e = r0;
    for (; e + 2 <= r1; e += 2) {           // 2 independent chains for MLP
        int s0 = colv[e], s1 = colv[e + 1];
        float w0 = invs[s0], w1 = invs[s1];
        uint4 v0 = *(const uint4*)&t[(size_t)s0 * 512 + d0];
        uint4 v1 = *(const uint4*)&t[(size_t)s1 * 512 + d0];
        acc[0] += w0 * blo(v0.x) + w1 * blo(v1.x);
        acc[1] += w0 * bhi(v0.x) + w1 * bhi(v1.x);
        acc[2] += w0 * blo(v0.y) + w1 * blo(v1.y);
        acc[3] += w0 * bhi(v0.y) + w1 * bhi(v1.y);
        acc[4] += w0 * blo(v0.z) + w1 * blo(v1.z);
        acc[5] += w0 * bhi(v0.z) + w1 * bhi(v1.z);
        acc[6] += w0 * blo(v0.w) + w1 * blo(v1.w);
        acc[7] += w0 * bhi(v0.w) + w1 * bhi(v1.w);
    }
    if (e < r1) {
        int s = colv[e];
        float ws = invs[s];
        uint4 v = *(const uint4*)&t[(size_t)s * 512 + d0];
        acc[0] += ws * blo(v.x); acc[1] += ws * bhi(v.x);
        acc[2] += ws * blo(v.y); acc[3] += ws * bhi(v.y);
        acc[4] += ws * blo(v.z); acc[5] += ws * bhi(v.z);
        acc[6] += ws * blo(v.w); acc[7] += ws * bhi(v.w);
    }
    float wd = invs[node], wdd = wd * wd;
    uint4 sv = *(const uint4*)&t[(size_t)node * 512 + d0];
    float sf[8] = {blo(sv.x), bhi(sv.x), blo(sv.y), bhi(sv.y), blo(sv.z), bhi(sv.z), blo(sv.w), bhi(sv.w)};
    float o[8];
#pragma unroll
    for (int k = 0; k < 8; k++) {
        float v = acc[k] * wd + sf[k] * wdd + bias[d0 + k];
        o[k] = v > 0.f ? v : 0.f;
    }
    uint4 pv;
    pv.x = pack2(o[0], o[1]); pv.y = pack2(o[2], o[3]);
    pv.z = pack2(o[4], o[5]); pv.w = pack2(o[6], o[7]);
    *(uint4*)&outp[(size_t)node * 512 + d0] = pv;
}

// ---------------- aggregation, 128-dim, +bias, hi/lo split out ----------------
__global__ __launch_bounds__(256) void agg128(const unsigned short* u, const int* rowptr,
                                              const int* colv, const float* invs,
                                              const float* bias, unsigned short* h2h, unsigned short* h2l) {
    int wave = threadIdx.x >> 6, lane = threadIdx.x & 63;
    int node = blockIdx.x * 4 + wave;
    int q = lane >> 4, ql = lane & 15;
    int d0 = ql * 8;
    float acc[8] = {0.f, 0.f, 0.f, 0.f, 0.f, 0.f, 0.f, 0.f};
    int r0 = rowptr[node], r1 = rowptr[node + 1];
    for (int e = r0 + q; e < r1; e += 4) {
        int s = colv[e];
        float ws = invs[s];
        uint4 v = *(const uint4*)&u[(size_t)s * 128 + d0];
        acc[0] += ws * blo(v.x); acc[1] += ws * bhi(v.x);
        acc[2] += ws * blo(v.y); acc[3] += ws * bhi(v.y);
        acc[4] += ws * blo(v.z); acc[5] += ws * bhi(v.z);
        acc[6] += ws * blo(v.w); acc[7] += ws * bhi(v.w);
    }
#pragma unroll
    for (int k = 0; k < 8; k++) {
        acc[k] += __shfl_xor(acc[k], 16);
        acc[k] += __shfl_xor(acc[k], 32);
    }
    float wd = invs[node], wdd = wd * wd;
    uint4 sv = *(const uint4*)&u[(size_t)node * 128 + d0];
    float sf[8] = {blo(sv.x), bhi(sv.x), blo(sv.y), bhi(sv.y), blo(sv.z), bhi(sv.z), blo(sv.w), bhi(sv.w)};
    unsigned short hh[8], hl[8];
#pragma unroll
    for (int k = 0; k < 8; k++) {
        float v = acc[k] * wd + sf[k] * wdd + bias[d0 + k];
        hh[k] = f2bf(v);
        hl[k] = f2bf(v - bf2f(hh[k]));
    }
    if (q == 0) {
        uint4 ph, pl;
        ph.x = ((unsigned)hh[1] << 16) | hh[0]; ph.y = ((unsigned)hh[3] << 16) | hh[2];
        ph.z = ((unsigned)hh[5] << 16) | hh[4]; ph.w = ((unsigned)hh[7] << 16) | hh[6];
        pl.x = ((unsigned)hl[1] << 16) | hl[0]; pl.y = ((unsigned)hl[3] << 16) | hl[2];
        pl.z = ((unsigned)hl[5] << 16) | hl[4]; pl.w = ((unsigned)hl[7] << 16) | hl[6];
        *(uint4*)&h2h[(size_t)node * 128 + d0] = ph;
        *(uint4*)&h2l[(size_t)node * 128 + d0] = pl;
    }
}

// ---------------- bilinear: s = T @ e^T, out = s*w + b ----------------
__global__ __launch_bounds__(256, 2) void bilinear_k(const unsigned short* Th, const unsigned short* Tl,
                                                     const unsigned short* Eh, const float* lin_w,
                                                     const float* lin_b, float* outp) {
    int tid = threadIdx.x, wave = tid >> 6, lane = tid & 63;
    int b = blockIdx.x >> 1, half = blockIdx.x & 1;
    int fr = lane & 15, q = lane >> 4;
    int irow0 = b * 256 + half * 128 + wave * 32;
    bf16x8 Ah[2][4], Al[2][4];
#pragma unroll
    for (int it = 0; it < 2; it++)
#pragma unroll
        for (int kk = 0; kk < 4; kk++) {
            size_t off = (size_t)(irow0 + it * 16 + fr) * 128 + kk * 32 + q * 8;
            Ah[it][kk] = *(const bf16x8*)&Th[off];
            Al[it][kk] = *(const bf16x8*)&Tl[off];
        }
    float w0 = lin_w[0], w1 = lin_w[1], c0 = lin_b[0], c1 = lin_b[1];
    for (int jt = 0; jt < 16; jt++) {
        bf16x8 Bf[4];
#pragma unroll
        for (int kk = 0; kk < 4; kk++)
            Bf[kk] = *(const bf16x8*)&Eh[(size_t)(b * 256 + jt * 16 + fr) * 128 + kk * 32 + q * 8];
#pragma unroll
        for (int it = 0; it < 2; it++) {
            f32x4 acc = (f32x4){0.f, 0.f, 0.f, 0.f};
#pragma unroll
            for (int kk = 0; kk < 4; kk++) {
                acc = __builtin_amdgcn_mfma_f32_16x16x32_bf16(Ah[it][kk], Bf[kk], acc, 0, 0, 0);
                acc = __builtin_amdgcn_mfma_f32_16x16x32_bf16(Al[it][kk], Bf[kk], acc, 0, 0, 0);
            }
#pragma unroll
            for (int r = 0; r < 4; r++) {
                int iloc = half * 128 + wave * 32 + it * 16 + q * 4 + r;
                int jloc = jt * 16 + fr;
                size_t o = ((size_t)b * 65536 + (size_t)iloc * 256 + jloc) * 2;
                float s = acc[r];
                float2 ov;
                ov.x = fmaf(s, w0, c0);
                ov.y = fmaf(s, w1, c1);
                *(float2*)&outp[o] = ov;
            }
        }
    }
}

extern "C" void kernel_launch(void* const* d_in, const int* in_sizes, int n_in,
                              void* d_out, int out_size, void* d_ws, size_t ws_size,
                              hipStream_t stream) {
    const float* x   = (const float*)d_in[0];
    const float* Wt1 = (const float*)d_in[1];
    const float* bt1 = (const float*)d_in[2];
    const float* Wt2 = (const float*)d_in[3];
    const float* bt2 = (const float*)d_in[4];
    const float* W1  = (const float*)d_in[5];
    const float* b1  = (const float*)d_in[6];
    const float* W2  = (const float*)d_in[7];
    const float* b2  = (const float*)d_in[8];
    const float* Mtx = (const float*)d_in[9];
    const float* lw  = (const float*)d_in[10];
    const float* lb  = (const float*)d_in[11];
    const int*   ei  = (const int*)d_in[12];
    int E = in_sizes[12] / 2;
    const int* srcp = ei;
    const int* dstp = ei + E;

    unsigned char* p = (unsigned char*)d_ws;
    size_t off = 0;
    auto alloc = [&](size_t bytes) -> void* {
        void* r = p + off;
        off = (off + bytes + 255) & ~(size_t)255;
        return r;
    };
    int*   cnt    = (int*)alloc((size_t)NN * 4);
    int*   rowptr = (int*)alloc(((size_t)NN + 1) * 4);
    int*   cursor = (int*)alloc((size_t)NN * 4);
    float* invs   = (float*)alloc((size_t)NN * 4);
    int*   bsum   = (int*)alloc(256 * 4);
    int*   boff   = (int*)alloc(256 * 4);
    int*   colv   = (int*)alloc((size_t)E * 4);
    unsigned short* Wcat   = (unsigned short*)alloc(524288 * 2);
    unsigned short* W1T    = (unsigned short*)alloc(262144 * 2);
    unsigned short* W2T    = (unsigned short*)alloc(65536 * 2);
    unsigned short* MTh    = (unsigned short*)alloc(16384 * 2);
    unsigned short* MTl    = (unsigned short*)alloc(16384 * 2);
    float*          cbias  = (float*)alloc(512 * 4);
    unsigned short* WcombT = (unsigned short*)alloc(524288 * 2);
    unsigned short* t1     = (unsigned short*)alloc((size_t)NN * 512 * 2);
    unsigned short* h1     = (unsigned short*)alloc((size_t)NN * 512 * 2);
    unsigned short* uu     = (unsigned short*)alloc((size_t)NN * 128 * 2);
    // aliases (lifetimes disjoint): T over t1, h2 over h1
    unsigned short* Th  = t1;
    unsigned short* Tl  = t1 + (size_t)NN * 128;
    unsigned short* h2h = h1;
    unsigned short* h2l = h1 + (size_t)NN * 128;

    hipMemsetAsync(cnt, 0, (size_t)NN * 4, stream);
    prep_pack<<<3392, 256, 0, stream>>>(Wt1, Wt2, W1, W2, Mtx, Wcat, W1T, W2T, MTh, MTl);
    cbias_k<<<16, 256, 0, stream>>>(bt1, bt2, W1, cbias);
    count_k<<<(E + 255) / 256, 256, 0, stream>>>(dstp, cnt, E);
    red_k<<<256, 256, 0, stream>>>(cnt, bsum);
    scanb_k<<<1, 256, 0, stream>>>(bsum, boff);
    scanf_k<<<256, 256, 0, stream>>>(cnt, boff, rowptr, cursor, invs);
    fill_k<<<(E + 255) / 256, 256, 0, stream>>>(srcp, dstp, cursor, colv, E);
    // WcombT[512][1024] = (Wcat @ W1)^T = W1T @ Wcat^T
    gemm_bt<<<dim3(8, 4), 256, 0, stream>>>(W1T, Wcat, WcombT, nullptr, 512, 1024, 512);
    // t1 = x @ Wcomb + cbias   [65536,512]
    gemm_f32a<<<2048, 256, 0, stream>>>(x, WcombT, t1, cbias);
    // h1 = relu(A @ t1 + b1)
    agg512<<<NN / 4, 256, 0, stream>>>(t1, rowptr, colv, invs, b1, h1);
    // u = h1 @ W2   [65536,128]
    gemm_bt<<<dim3(1, 512), 256, 0, stream>>>(h1, W2T, uu, nullptr, NN, 128, 512);
    // h2 = A @ u + b2 (hi/lo split)
    agg128<<<NN / 4, 256, 0, stream>>>(uu, rowptr, colv, invs, b2, h2h, h2l);
    // T = h2 @ M (split)
    gemm_T<<<512, 256, 0, stream>>>(h2h, h2l, MTh, MTl, Th, Tl);
    // scores + Linear(1,2)
    bilinear_k<<<512, 256, 0, stream>>>(Th, Tl, h2h, lw, lb, (float*)d_out);
}

// Round 3
// 919.133 us; speedup vs baseline: 1.0360x; 1.0211x over previous
//
#include <hip/hip_runtime.h>
#include <stdint.h>

#define NN 65536

typedef __attribute__((ext_vector_type(8))) short bf16x8;
typedef __attribute__((ext_vector_type(4))) float f32x4;

__device__ __forceinline__ unsigned short f2bf(float f) {
    unsigned u = __float_as_uint(f);
    u += 0x7fffu + ((u >> 16) & 1u);
    return (unsigned short)(u >> 16);
}
__device__ __forceinline__ float bf2f(unsigned short h) { return __uint_as_float(((unsigned)h) << 16); }
__device__ __forceinline__ float blo(unsigned u) { return __uint_as_float(u << 16); }
__device__ __forceinline__ float bhi(unsigned u) { return __uint_as_float(u & 0xffff0000u); }
__device__ __forceinline__ unsigned pack2(float a, float b) {
    return ((unsigned)f2bf(b) << 16) | (unsigned)f2bf(a);
}
// lo16 = hi16(x) [trunc-to-bf16], hi16 = hi16(y)
__device__ __forceinline__ unsigned trunc2(float x, float y) {
    return __builtin_amdgcn_perm(__float_as_uint(y), __float_as_uint(x), 0x07060302u);
}

__device__ __forceinline__ void gl_lds16(const void* g, void* l) {
    __builtin_amdgcn_global_load_lds((const __attribute__((address_space(1))) void*)g,
                                     (__attribute__((address_space(3))) void*)l, 16, 0, 0);
}

// ---------------- prep: pack/transpose weights to bf16 ----------------
__global__ void prep_pack(const float* Wt1, const float* Wt2, const float* W1,
                          const float* W2, const float* Mtx,
                          unsigned short* Wcat, unsigned short* W1T,
                          unsigned short* W2T, unsigned short* MTh, unsigned short* MTl) {
    int i = blockIdx.x * 256 + threadIdx.x;
    if (i < 524288) {                       // Wcat [1024][512]
        int k = i >> 9, j = i & 511;
        float v = (k < 256) ? Wt1[k * 512 + j] : Wt2[(k - 256) * 512 + j];
        Wcat[i] = f2bf(v);
    } else if (i < 786432) {                // W1T [512][512]
        int t = i - 524288; int n = t >> 9, j = t & 511;
        W1T[t] = f2bf(W1[j * 512 + n]);
    } else if (i < 851968) {                // W2T [128][512]
        int t = i - 786432; int n = t >> 9, j = t & 511;
        W2T[t] = f2bf(W2[j * 128 + n]);
    } else if (i < 868352) {                // MT [128][128] hi/lo, MT[r][c]=M[c][r]
        int t = i - 851968; int d = t >> 7, e = t & 127;
        float m = Mtx[e * 128 + d];
        unsigned short h = f2bf(m);
        MTh[t] = h; MTl[t] = f2bf(m - bf2f(h));
    }
}

// cbias = (bt1+bt2) @ W1 — 16 blocks, K-partitioned reduction
__global__ void cbias_k(const float* bt1, const float* bt2, const float* W1, float* c) {
    __shared__ float sm[256];
    int t = threadIdx.x;
    int n = blockIdx.x * 32 + (t & 31);
    int jp = t >> 5;                        // 8 K-partitions of 64
    float acc = 0.f;
    for (int j = jp * 64; j < jp * 64 + 64; j++)
        acc += (bt1[j] + bt2[j]) * W1[j * 512 + n];
    sm[t] = acc;
    __syncthreads();
    if (t < 32) {
        float a = 0.f;
#pragma unroll
        for (int p = 0; p < 8; p++) a += sm[p * 32 + t];
        c[blockIdx.x * 32 + t] = a;
    }
}

// ---------------- CSR build ----------------
__global__ void count_k(const int* dst, int* cnt, int E) {
    int e = blockIdx.x * 256 + threadIdx.x;
    if (e < E) atomicAdd(&cnt[dst[e]], 1);
}
__global__ void red_k(const int* cnt, int* bsum) {
    __shared__ int sm[256];
    int tid = threadIdx.x;
    sm[tid] = cnt[blockIdx.x * 256 + tid];
    __syncthreads();
    for (int s = 128; s > 0; s >>= 1) {
        if (tid < s) sm[tid] += sm[tid + s];
        __syncthreads();
    }
    if (tid == 0) bsum[blockIdx.x] = sm[0];
}
__global__ void scanb_k(const int* bsum, int* boff) {
    __shared__ int sm[256];
    int tid = threadIdx.x;
    int v0 = bsum[tid];
    sm[tid] = v0;
    __syncthreads();
    for (int s = 1; s < 256; s <<= 1) {
        int t = sm[tid];
        if (tid >= s) t += sm[tid - s];
        __syncthreads();
        sm[tid] = t;
        __syncthreads();
    }
    boff[tid] = sm[tid] - v0;   // exclusive
}
__global__ void scanf_k(const int* cnt, const int* boff, int* rowptr, int* cursor, float* invs) {
    __shared__ int sm[256];
    int tid = threadIdx.x;
    int i = blockIdx.x * 256 + tid;
    int v = cnt[i];
    sm[tid] = v;
    __syncthreads();
    for (int s = 1; s < 256; s <<= 1) {
        int t = sm[tid];
        if (tid >= s) t += sm[tid - s];
        __syncthreads();
        sm[tid] = t;
        __syncthreads();
    }
    int incl = sm[tid];
    int base = boff[blockIdx.x];
    int excl = base + incl - v;
    rowptr[i] = excl;
    cursor[i] = excl;
    invs[i] = rsqrtf((float)(v + 1));
    if (i == NN - 1) rowptr[NN] = base + incl;
}
__global__ void fill_k(const int* src, const int* dst, int* cursor, int* colv, int E) {
    int e = blockIdx.x * 256 + threadIdx.x;
    if (e < E) {
        int d = dst[e];
        int p = atomicAdd(&cursor[d], 1);
        colv[p] = src[e];
    }
}

// ---------------- generic bf16 GEMM: C[M,N] = A[M,K] @ BT[N,K]^T (+bias[col]) ----------------
__global__ __launch_bounds__(256, 2) void gemm_bt(const unsigned short* A, const unsigned short* BT,
                                                  unsigned short* C, const float* bias,
                                                  int M, int N, int K) {
    __shared__ __align__(16) unsigned short sA[128 * 32];
    __shared__ __align__(16) unsigned short sB[128 * 32];
    int tid = threadIdx.x, wave = tid >> 6, lane = tid & 63;
    int bm = blockIdx.y * 128, bn = blockIdx.x * 128;
    int wm = (wave >> 1) * 64, wn = (wave & 1) * 64;
    f32x4 acc[4][4];
#pragma unroll
    for (int i = 0; i < 4; i++)
#pragma unroll
        for (int j = 0; j < 4; j++) acc[i][j] = (f32x4){0.f, 0.f, 0.f, 0.f};
    int sr = wave * 32 + (lane >> 2);
    int sc = (lane & 3) * 8;
    const int fr = lane & 15;
    const int fk = (lane >> 4) * 8;
    for (int k0 = 0; k0 < K; k0 += 32) {
        const unsigned short* ga = A + (size_t)(bm + sr) * K + k0 + sc;
        gl_lds16(ga, &sA[sr * 32 + sc]);
        gl_lds16(ga + (size_t)16 * K, &sA[(sr + 16) * 32 + sc]);
        const unsigned short* gb = BT + (size_t)(bn + sr) * K + k0 + sc;
        gl_lds16(gb, &sB[sr * 32 + sc]);
        gl_lds16(gb + (size_t)16 * K, &sB[(sr + 16) * 32 + sc]);
        __syncthreads();
        bf16x8 af[4], bfr[4];
#pragma unroll
        for (int i = 0; i < 4; i++) af[i] = *(const bf16x8*)&sA[(wm + i * 16 + fr) * 32 + fk];
#pragma unroll
        for (int j = 0; j < 4; j++) bfr[j] = *(const bf16x8*)&sB[(wn + j * 16 + fr) * 32 + fk];
#pragma unroll
        for (int i = 0; i < 4; i++)
#pragma unroll
            for (int j = 0; j < 4; j++)
                acc[i][j] = __builtin_amdgcn_mfma_f32_16x16x32_bf16(af[i], bfr[j], acc[i][j], 0, 0, 0);
        __syncthreads();
    }
    int rq = (lane >> 4) * 4;
#pragma unroll
    for (int i = 0; i < 4; i++)
#pragma unroll
        for (int j = 0; j < 4; j++) {
            int col = bn + wn + j * 16 + fr;
            float bb = bias ? bias[col] : 0.f;
#pragma unroll
            for (int r = 0; r < 4; r++) {
                int row = bm + wm + i * 16 + rq + r;
                C[(size_t)row * N + col] = f2bf(acc[i][j][r] + bb);
            }
        }
}

// ---------------- GEMM1: t1 = x[65536,1024] @ WcombT^T + cbias ----------------
// m97 2-barrier structure. A stays fp32 in LDS, staged via global_load_lds with
// XOR-swizzled 16B chunks (fp32 rows are 128B = bank-aligned; chunk^(row&7)
// makes fragment ds_reads 2-way conflicts = free). Fragments converted to bf16
// read-side by truncating v_perm packs. XCD swizzle keeps the 4 bn-tiles of one
// bm on one XCD's L2.
__global__ __launch_bounds__(256, 2) void gemm_f32a(const float* A, const unsigned short* BT,
                                                    unsigned short* C, const float* bias) {
    const int K = 1024, N = 512;
    __shared__ __align__(16) float sAf[128 * 32];          // 16 KB
    __shared__ __align__(16) unsigned short sB[128 * 32];  // 8 KB
    int tid = threadIdx.x, wave = tid >> 6, lane = tid & 63;
    int b = blockIdx.x;
    int xcd = b & 7, jn = (b >> 3) & 3, tt = b >> 5;
    int bm = (tt * 8 + xcd) * 128, bn = jn * 128;
    int wm = (wave >> 1) * 64, wn = (wave & 1) * 64;
    f32x4 acc[4][4];
#pragma unroll
    for (int i = 0; i < 4; i++)
#pragma unroll
        for (int j = 0; j < 4; j++) acc[i][j] = (f32x4){0.f, 0.f, 0.f, 0.f};
    // B staging (bf16, proven layout)
    int sr = wave * 32 + (lane >> 2);
    int sc = (lane & 3) * 8;
    // A staging: per wave 4 DMA instrs, instr i covers rows wave*32+i*8 .. +7;
    // lane L -> row (L>>3), LDS chunk-slot (L&7); source global chunk = slot ^ (row&7)
    int arow = lane >> 3;                    // 0..7
    int achk = (lane & 7) ^ arow;            // swizzled source chunk
    const int fr = lane & 15;
    const int fk = (lane >> 4) * 8;
    const float* Abase = A + (size_t)(bm + wave * 32 + arow) * K + achk * 4;
    const unsigned short* Bbase = BT + (size_t)(bn + sr) * K + sc;
    for (int k0 = 0; k0 < K; k0 += 32) {
#pragma unroll
        for (int i = 0; i < 4; i++)
            gl_lds16(Abase + (size_t)(8 * i) * K + k0, &sAf[(wave * 32 + i * 8) * 32]);
        gl_lds16(Bbase + k0, &sB[sr * 32 + sc]);
        gl_lds16(Bbase + (size_t)16 * K + k0, &sB[(sr + 16) * 32 + sc]);
        __syncthreads();
        bf16x8 af[4], bfr[4];
#pragma unroll
        for (int i = 0; i < 4; i++) {
            int r = wm + i * 16 + fr;
            int s = r & 7;
            int c0 = fk >> 2;
            float4 fa = *(const float4*)&sAf[r * 32 + ((c0 ^ s) << 2)];
            float4 fb = *(const float4*)&sAf[r * 32 + (((c0 + 1) ^ s) << 2)];
            union { unsigned u[4]; bf16x8 v; } t;
            t.u[0] = trunc2(fa.x, fa.y);
            t.u[1] = trunc2(fa.z, fa.w);
            t.u[2] = trunc2(fb.x, fb.y);
            t.u[3] = trunc2(fb.z, fb.w);
            af[i] = t.v;
        }
#pragma unroll
        for (int j = 0; j < 4; j++) bfr[j] = *(const bf16x8*)&sB[(wn + j * 16 + fr) * 32 + fk];
#pragma unroll
        for (int i = 0; i < 4; i++)
#pragma unroll
            for (int j = 0; j < 4; j++)
                acc[i][j] = __builtin_amdgcn_mfma_f32_16x16x32_bf16(af[i], bfr[j], acc[i][j], 0, 0, 0);
        __syncthreads();
    }
    int rq = (lane >> 4) * 4;
#pragma unroll
    for (int i = 0; i < 4; i++)
#pragma unroll
        for (int j = 0; j < 4; j++) {
            int col = bn + wn + j * 16 + fr;
            float bb = bias[col];
#pragma unroll
            for (int r = 0; r < 4; r++) {
                int row = bm + wm + i * 16 + rq + r;
                C[(size_t)row * N + col] = f2bf(acc[i][j][r] + bb);
            }
        }
}

// ---------------- T = h2 @ M with hi/lo split (3 phases), split output ----------------
__global__ __launch_bounds__(256, 2) void gemm_T(const unsigned short* h2h, const unsigned short* h2l,
                                                 const unsigned short* MTh, const unsigned short* MTl,
                                                 unsigned short* Th, unsigned short* Tl) {
    __shared__ __align__(16) unsigned short sA[128 * 32];
    __shared__ __align__(16) unsigned short sB[128 * 32];
    int tid = threadIdx.x, wave = tid >> 6, lane = tid & 63;
    int bm = blockIdx.x * 128;
    int wm = (wave >> 1) * 64, wn = (wave & 1) * 64;
    f32x4 acc[4][4];
#pragma unroll
    for (int i = 0; i < 4; i++)
#pragma unroll
        for (int j = 0; j < 4; j++) acc[i][j] = (f32x4){0.f, 0.f, 0.f, 0.f};
    int sr = wave * 32 + (lane >> 2);
    int sc = (lane & 3) * 8;
    const int fr = lane & 15;
    const int fk = (lane >> 4) * 8;
    const unsigned short* APs[3] = {h2h, h2h, h2l};
    const unsigned short* BPs[3] = {MTh, MTl, MTh};
    for (int it = 0; it < 12; it++) {
        int ph = it >> 2, k0 = (it & 3) * 32;
        const unsigned short* ga = APs[ph] + (size_t)(bm + sr) * 128 + k0 + sc;
        gl_lds16(ga, &sA[sr * 32 + sc]);
        gl_lds16(ga + 16 * 128, &sA[(sr + 16) * 32 + sc]);
        const unsigned short* gb = BPs[ph] + (size_t)sr * 128 + k0 + sc;
        gl_lds16(gb, &sB[sr * 32 + sc]);
        gl_lds16(gb + 16 * 128, &sB[(sr + 16) * 32 + sc]);
        __syncthreads();
        bf16x8 af[4], bfr[4];
#pragma unroll
        for (int i = 0; i < 4; i++) af[i] = *(const bf16x8*)&sA[(wm + i * 16 + fr) * 32 + fk];
#pragma unroll
        for (int j = 0; j < 4; j++) bfr[j] = *(const bf16x8*)&sB[(wn + j * 16 + fr) * 32 + fk];
#pragma unroll
        for (int i = 0; i < 4; i++)
#pragma unroll
            for (int j = 0; j < 4; j++)
                acc[i][j] = __builtin_amdgcn_mfma_f32_16x16x32_bf16(af[i], bfr[j], acc[i][j], 0, 0, 0);
        __syncthreads();
    }
    int rq = (lane >> 4) * 4;
#pragma unroll
    for (int i = 0; i < 4; i++)
#pragma unroll
        for (int j = 0; j < 4; j++) {
            int col = wn + j * 16 + fr;
#pragma unroll
            for (int r = 0; r < 4; r++) {
                int row = bm + wm + i * 16 + rq + r;
                float v = acc[i][j][r];
                unsigned short h = f2bf(v);
                Th[(size_t)row * 128 + col] = h;
                Tl[(size_t)row * 128 + col] = f2bf(v - bf2f(h));
            }
        }
}

// ---------------- aggregation, 512-dim, +bias, relu, bf16 out (4 chains) ----------------
__global__ __launch_bounds__(256) void agg512(const unsigned short* t, const int* rowptr,
                                              const int* colv, const float* invs,
                                              const float* bias, unsigned short* outp) {
    int wave = threadIdx.x >> 6, lane = threadIdx.x & 63;
    int node = blockIdx.x * 4 + wave;
    int d0 = lane * 8;
    float acc[8] = {0.f, 0.f, 0.f, 0.f, 0.f, 0.f, 0.f, 0.f};
    int r0 = rowptr[node], r1 = rowptr[node + 1];
    int e = r0;
    for (; e + 4 <= r1; e += 4) {           // 4 independent chains
        int s0 = colv[e], s1 = colv[e + 1], s2 = colv[e + 2], s3 = colv[e + 3];
        float w0 = invs[s0], w1 = invs[s1], w2 = invs[s2], w3 = invs[s3];
        uint4 v0 = *(const uint4*)&t[(size_t)s0 * 512 + d0];
        uint4 v1 = *(const uint4*)&t[(size_t)s1 * 512 + d0];
        uint4 v2 = *(const uint4*)&t[(size_t)s2 * 512 + d0];
        uint4 v3 = *(const uint4*)&t[(size_t)s3 * 512 + d0];
        acc[0] += w0 * blo(v0.x) + w1 * blo(v1.x) + w2 * blo(v2.x) + w3 * blo(v3.x);
        acc[1] += w0 * bhi(v0.x) + w1 * bhi(v1.x) + w2 * bhi(v2.x) + w3 * bhi(v3.x);
        acc[2] += w0 * blo(v0.y) + w1 * blo(v1.y) + w2 * blo(v2.y) + w3 * blo(v3.y);
        acc[3] += w0 * bhi(v0.y) + w1 * bhi(v1.y) + w2 * bhi(v2.y) + w3 * bhi(v3.y);
        acc[4] += w0 * blo(v0.z) + w1 * blo(v1.z) + w2 * blo(v2.z) + w3 * blo(v3.z);
        acc[5] += w0 * bhi(v0.z) + w1 * bhi(v1.z) + w2 * bhi(v2.z) + w3 * bhi(v3.z);
        acc[6] += w0 * blo(v0.w) + w1 * blo(v1.w) + w2 * blo(v2.w) + w3 * blo(v3.w);
        acc[7] += w0 * bhi(v0.w) + w1 * bhi(v1.w) + w2 * bhi(v2.w) + w3 * bhi(v3.w);
    }
    for (; e < r1; e++) {
        int s = colv[e];
        float ws = invs[s];
        uint4 v = *(const uint4*)&t[(size_t)s * 512 + d0];
        acc[0] += ws * blo(v.x); acc[1] += ws * bhi(v.x);
        acc[2] += ws * blo(v.y); acc[3] += ws * bhi(v.y);
        acc[4] += ws * blo(v.z); acc[5] += ws * bhi(v.z);
        acc[6] += ws * blo(v.w); acc[7] += ws * bhi(v.w);
    }
    float wd = invs[node], wdd = wd * wd;
    uint4 sv = *(const uint4*)&t[(size_t)node * 512 + d0];
    float sf[8] = {blo(sv.x), bhi(sv.x), blo(sv.y), bhi(sv.y), blo(sv.z), bhi(sv.z), blo(sv.w), bhi(sv.w)};
    float o[8];
#pragma unroll
    for (int k = 0; k < 8; k++) {
        float v = acc[k] * wd + sf[k] * wdd + bias[d0 + k];
        o[k] = v > 0.f ? v : 0.f;
    }
    uint4 pv;
    pv.x = pack2(o[0], o[1]); pv.y = pack2(o[2], o[3]);
    pv.z = pack2(o[4], o[5]); pv.w = pack2(o[6], o[7]);
    *(uint4*)&outp[(size_t)node * 512 + d0] = pv;
}

// ---------------- aggregation, 128-dim, +bias, hi/lo split out ----------------
__global__ __launch_bounds__(256) void agg128(const unsigned short* u, const int* rowptr,
                                              const int* colv, const float* invs,
                                              const float* bias, unsigned short* h2h, unsigned short* h2l) {
    int wave = threadIdx.x >> 6, lane = threadIdx.x & 63;
    int node = blockIdx.x * 4 + wave;
    int q = lane >> 4, ql = lane & 15;
    int d0 = ql * 8;
    float acc[8] = {0.f, 0.f, 0.f, 0.f, 0.f, 0.f, 0.f, 0.f};
    int r0 = rowptr[node], r1 = rowptr[node + 1];
    for (int e = r0 + q; e < r1; e += 4) {
        int s = colv[e];
        float ws = invs[s];
        uint4 v = *(const uint4*)&u[(size_t)s * 128 + d0];
        acc[0] += ws * blo(v.x); acc[1] += ws * bhi(v.x);
        acc[2] += ws * blo(v.y); acc[3] += ws * bhi(v.y);
        acc[4] += ws * blo(v.z); acc[5] += ws * bhi(v.z);
        acc[6] += ws * blo(v.w); acc[7] += ws * bhi(v.w);
    }
#pragma unroll
    for (int k = 0; k < 8; k++) {
        acc[k] += __shfl_xor(acc[k], 16);
        acc[k] += __shfl_xor(acc[k], 32);
    }
    float wd = invs[node], wdd = wd * wd;
    uint4 sv = *(const uint4*)&u[(size_t)node * 128 + d0];
    float sf[8] = {blo(sv.x), bhi(sv.x), blo(sv.y), bhi(sv.y), blo(sv.z), bhi(sv.z), blo(sv.w), bhi(sv.w)};
    unsigned short hh[8], hl[8];
#pragma unroll
    for (int k = 0; k < 8; k++) {
        float v = acc[k] * wd + sf[k] * wdd + bias[d0 + k];
        hh[k] = f2bf(v);
        hl[k] = f2bf(v - bf2f(hh[k]));
    }
    if (q == 0) {
        uint4 ph, pl;
        ph.x = ((unsigned)hh[1] << 16) | hh[0]; ph.y = ((unsigned)hh[3] << 16) | hh[2];
        ph.z = ((unsigned)hh[5] << 16) | hh[4]; ph.w = ((unsigned)hh[7] << 16) | hh[6];
        pl.x = ((unsigned)hl[1] << 16) | hl[0]; pl.y = ((unsigned)hl[3] << 16) | hl[2];
        pl.z = ((unsigned)hl[5] << 16) | hl[4]; pl.w = ((unsigned)hl[7] << 16) | hl[6];
        *(uint4*)&h2h[(size_t)node * 128 + d0] = ph;
        *(uint4*)&h2l[(size_t)node * 128 + d0] = pl;
    }
}

// ---------------- bilinear: s = T @ e^T, out = s*w + b ----------------
__global__ __launch_bounds__(256, 2) void bilinear_k(const unsigned short* Th, const unsigned short* Tl,
                                                     const unsigned short* Eh, const float* lin_w,
                                                     const float* lin_b, float* outp) {
    int tid = threadIdx.x, wave = tid >> 6, lane = tid & 63;
    int b = blockIdx.x >> 1, half = blockIdx.x & 1;
    int fr = lane & 15, q = lane >> 4;
    int irow0 = b * 256 + half * 128 + wave * 32;
    bf16x8 Ah[2][4], Al[2][4];
#pragma unroll
    for (int it = 0; it < 2; it++)
#pragma unroll
        for (int kk = 0; kk < 4; kk++) {
            size_t off = (size_t)(irow0 + it * 16 + fr) * 128 + kk * 32 + q * 8;
            Ah[it][kk] = *(const bf16x8*)&Th[off];
            Al[it][kk] = *(const bf16x8*)&Tl[off];
        }
    float w0 = lin_w[0], w1 = lin_w[1], c0 = lin_b[0], c1 = lin_b[1];
    for (int jt = 0; jt < 16; jt++) {
        bf16x8 Bf[4];
#pragma unroll
        for (int kk = 0; kk < 4; kk++)
            Bf[kk] = *(const bf16x8*)&Eh[(size_t)(b * 256 + jt * 16 + fr) * 128 + kk * 32 + q * 8];
#pragma unroll
        for (int it = 0; it < 2; it++) {
            f32x4 acc = (f32x4){0.f, 0.f, 0.f, 0.f};
#pragma unroll
            for (int kk = 0; kk < 4; kk++) {
                acc = __builtin_amdgcn_mfma_f32_16x16x32_bf16(Ah[it][kk], Bf[kk], acc, 0, 0, 0);
                acc = __builtin_amdgcn_mfma_f32_16x16x32_bf16(Al[it][kk], Bf[kk], acc, 0, 0, 0);
            }
#pragma unroll
            for (int r = 0; r < 4; r++) {
                int iloc = half * 128 + wave * 32 + it * 16 + q * 4 + r;
                int jloc = jt * 16 + fr;
                size_t o = ((size_t)b * 65536 + (size_t)iloc * 256 + jloc) * 2;
                float s = acc[r];
                float2 ov;
                ov.x = fmaf(s, w0, c0);
                ov.y = fmaf(s, w1, c1);
                *(float2*)&outp[o] = ov;
            }
        }
    }
}

extern "C" void kernel_launch(void* const* d_in, const int* in_sizes, int n_in,
                              void* d_out, int out_size, void* d_ws, size_t ws_size,
                              hipStream_t stream) {
    const float* x   = (const float*)d_in[0];
    const float* Wt1 = (const float*)d_in[1];
    const float* bt1 = (const float*)d_in[2];
    const float* Wt2 = (const float*)d_in[3];
    const float* bt2 = (const float*)d_in[4];
    const float* W1  = (const float*)d_in[5];
    const float* b1  = (const float*)d_in[6];
    const float* W2  = (const float*)d_in[7];
    const float* b2  = (const float*)d_in[8];
    const float* Mtx = (const float*)d_in[9];
    const float* lw  = (const float*)d_in[10];
    const float* lb  = (const float*)d_in[11];
    const int*   ei  = (const int*)d_in[12];
    int E = in_sizes[12] / 2;
    const int* srcp = ei;
    const int* dstp = ei + E;

    unsigned char* p = (unsigned char*)d_ws;
    size_t off = 0;
    auto alloc = [&](size_t bytes) -> void* {
        void* r = p + off;
        off = (off + bytes + 255) & ~(size_t)255;
        return r;
    };
    int*   cnt    = (int*)alloc((size_t)NN * 4);
    int*   rowptr = (int*)alloc(((size_t)NN + 1) * 4);
    int*   cursor = (int*)alloc((size_t)NN * 4);
    float* invs   = (float*)alloc((size_t)NN * 4);
    int*   bsum   = (int*)alloc(256 * 4);
    int*   boff   = (int*)alloc(256 * 4);
    int*   colv   = (int*)alloc((size_t)E * 4);
    unsigned short* Wcat   = (unsigned short*)alloc(524288 * 2);
    unsigned short* W1T    = (unsigned short*)alloc(262144 * 2);
    unsigned short* W2T    = (unsigned short*)alloc(65536 * 2);
    unsigned short* MTh    = (unsigned short*)alloc(16384 * 2);
    unsigned short* MTl    = (unsigned short*)alloc(16384 * 2);
    float*          cbias  = (float*)alloc(512 * 4);
    unsigned short* WcombT = (unsigned short*)alloc(524288 * 2);
    unsigned short* t1     = (unsigned short*)alloc((size_t)NN * 512 * 2);
    unsigned short* h1     = (unsigned short*)alloc((size_t)NN * 512 * 2);
    unsigned short* uu     = (unsigned short*)alloc((size_t)NN * 128 * 2);
    // aliases (lifetimes disjoint): T over t1, h2 over h1
    unsigned short* Th  = t1;
    unsigned short* Tl  = t1 + (size_t)NN * 128;
    unsigned short* h2h = h1;
    unsigned short* h2l = h1 + (size_t)NN * 128;

    hipMemsetAsync(cnt, 0, (size_t)NN * 4, stream);
    prep_pack<<<3392, 256, 0, stream>>>(Wt1, Wt2, W1, W2, Mtx, Wcat, W1T, W2T, MTh, MTl);
    cbias_k<<<16, 256, 0, stream>>>(bt1, bt2, W1, cbias);
    count_k<<<(E + 255) / 256, 256, 0, stream>>>(dstp, cnt, E);
    red_k<<<256, 256, 0, stream>>>(cnt, bsum);
    scanb_k<<<1, 256, 0, stream>>>(bsum, boff);
    scanf_k<<<256, 256, 0, stream>>>(cnt, boff, rowptr, cursor, invs);
    fill_k<<<(E + 255) / 256, 256, 0, stream>>>(srcp, dstp, cursor, colv, E);
    // WcombT[512][1024] = (Wcat @ W1)^T = W1T @ Wcat^T
    gemm_bt<<<dim3(8, 4), 256, 0, stream>>>(W1T, Wcat, WcombT, nullptr, 512, 1024, 512);
    // t1 = x @ Wcomb + cbias   [65536,512]
    gemm_f32a<<<2048, 256, 0, stream>>>(x, WcombT, t1, cbias);
    // h1 = relu(A @ t1 + b1)
    agg512<<<NN / 4, 256, 0, stream>>>(t1, rowptr, colv, invs, b1, h1);
    // u = h1 @ W2   [65536,128]
    gemm_bt<<<dim3(1, 512), 256, 0, stream>>>(h1, W2T, uu, nullptr, NN, 128, 512);
    // h2 = A @ u + b2 (hi/lo split)
    agg128<<<NN / 4, 256, 0, stream>>>(uu, rowptr, colv, invs, b2, h2h, h2l);
    // T = h2 @ M (split)
    gemm_T<<<512, 256, 0, stream>>>(h2h, h2l, MTh, MTl, Th, Tl);
    // scores + Linear(1,2)
    bilinear_k<<<512, 256, 0, stream>>>(Th, Tl, h2h, lw, lb, (float*)d_out);
}